// Round 2
// baseline (276.054 us; speedup 1.0000x reference)
//
#include <hip/hip_runtime.h>
#include <hip/hip_bf16.h>

// QuantLinear: out[t,o] = scale[o] * sum_k x[t,k]*q[o,k] + bias[o]
// M=32, N=11008, K=4096.
// Harness dtype model (round-1 evidence): fp16 tensors are promoted to
// float32 (inputs AND output); int8 weight widened to int32.
//   d_in[0] x      : float32 [32][4096]
//   d_in[1] qweight: int32   [11008][4096]   (values in [-128,127])
//   d_in[2] scales : float32 [11008]
//   d_in[3] bias   : float32 [11008]
//   d_out   out    : float32 [32][11008]
// Memory-bound: 180.4 MB weight stream -> ~29 us floor @6.3 TB/s.
// Strategy: bf16 MFMA. int8 is exactly representable in bf16 (cvt_f32_i32 +
// take-high-16 is exact); x is truncated f32->bf16 (<=3 mantissa bits lost,
// error ~0.1 vs threshold 3.92). Fragments straight from global (x is
// L2-resident, w streams from HBM), scale/bias in fp32 epilogue.

constexpr int IN_F  = 4096;
constexpr int OUT_F = 11008;

typedef short bf16x8 __attribute__((ext_vector_type(8)));  // 8 bf16 (4 VGPRs)
typedef float f32x4  __attribute__((ext_vector_type(4)));

union B8 { bf16x8 v; unsigned u[4]; };

// Pack hi16(lo-float) into low half, hi16(hi-float) into high half:
// element order [lo, hi] as bf16 pair. Truncation toward zero — exact for
// int8 values, <=2^-8 rel err for x.
__device__ __forceinline__ unsigned pack2f(float lo, float hi) {
    return __builtin_amdgcn_perm(__float_as_uint(hi),
                                 __float_as_uint(lo),
                                 0x07060302u);
}

__global__ __launch_bounds__(256, 4)
void qlin_kernel(const float* __restrict__ x,       // [32][4096]
                 const int* __restrict__ w,         // [11008][4096]
                 const float* __restrict__ scales,  // [11008]
                 const float* __restrict__ bias,    // [11008]
                 float* __restrict__ out)           // [32][11008]
{
    const int lane = threadIdx.x & 63;
    const int wv   = threadIdx.x >> 6;   // 0..3: K-split across the 4 waves
    const int r    = lane & 15;
    const int q    = lane >> 4;

    const int n0 = blockIdx.x << 4;      // 688 blocks x 16 output rows
    const int kb = wv << 10;             // 1024-wide K slice per wave

    f32x4 acc0 = {0.f, 0.f, 0.f, 0.f};   // tokens 0..15
    f32x4 acc1 = {0.f, 0.f, 0.f, 0.f};   // tokens 16..31

    // A-frag: x[m = r][k = kb + q*8 + j]  (L2-resident, 512 KB total)
    const float* xp0 = x + r * IN_F + kb + q * 8;
    const float* xp1 = xp0 + 16 * IN_F;
    // B-frag: w[n = n0+r][k = kb + q*8 + j], 8 int32 = 2x dwordx4 per lane
    const int* wp = w + (size_t)(n0 + r) * IN_F + kb + q * 8;

    #pragma unroll 2
    for (int kk = 0; kk < 1024; kk += 32) {
        float4 xa = *reinterpret_cast<const float4*>(xp0 + kk);
        float4 xb = *reinterpret_cast<const float4*>(xp0 + kk + 4);
        float4 xc = *reinterpret_cast<const float4*>(xp1 + kk);
        float4 xd = *reinterpret_cast<const float4*>(xp1 + kk + 4);
        int4   qa = *reinterpret_cast<const int4*>(wp + kk);
        int4   qb = *reinterpret_cast<const int4*>(wp + kk + 4);

        B8 a0, a1, bb;
        a0.u[0] = pack2f(xa.x, xa.y);  a0.u[1] = pack2f(xa.z, xa.w);
        a0.u[2] = pack2f(xb.x, xb.y);  a0.u[3] = pack2f(xb.z, xb.w);
        a1.u[0] = pack2f(xc.x, xc.y);  a1.u[1] = pack2f(xc.z, xc.w);
        a1.u[2] = pack2f(xd.x, xd.y);  a1.u[3] = pack2f(xd.z, xd.w);
        bb.u[0] = pack2f((float)qa.x, (float)qa.y);
        bb.u[1] = pack2f((float)qa.z, (float)qa.w);
        bb.u[2] = pack2f((float)qb.x, (float)qb.y);
        bb.u[3] = pack2f((float)qb.z, (float)qb.w);

        acc0 = __builtin_amdgcn_mfma_f32_16x16x32_bf16(a0.v, bb.v, acc0, 0, 0, 0);
        acc1 = __builtin_amdgcn_mfma_f32_16x16x32_bf16(a1.v, bb.v, acc1, 0, 0, 0);
    }

    // Cross-wave K reduction through LDS (once per block).
    __shared__ float red[3][2][4][64];
    if (wv > 0) {
        #pragma unroll
        for (int i = 0; i < 4; ++i) {
            red[wv - 1][0][i][lane] = acc0[i];
            red[wv - 1][1][i][lane] = acc1[i];
        }
    }
    __syncthreads();
    if (wv == 0) {
        #pragma unroll
        for (int j = 0; j < 3; ++j) {
            #pragma unroll
            for (int i = 0; i < 4; ++i) {
                acc0[i] += red[j][0][i][lane];
                acc1[i] += red[j][1][i][lane];
            }
        }
        // C/D layout (verified m89/m91): col n = lane&15, row m = (lane>>4)*4 + reg
        const int n = n0 + r;
        const float s = scales[n];
        const float b = bias[n];
        #pragma unroll
        for (int i = 0; i < 4; ++i) {
            out[(q * 4 + i) * OUT_F + n]      = acc0[i] * s + b;
            out[(16 + q * 4 + i) * OUT_F + n] = acc1[i] * s + b;
        }
    }
}

extern "C" void kernel_launch(void* const* d_in, const int* in_sizes, int n_in,
                              void* d_out, int out_size, void* d_ws, size_t ws_size,
                              hipStream_t stream) {
    const float* x      = (const float*)d_in[0];
    const int*   w      = (const int*)d_in[1];
    const float* scales = (const float*)d_in[2];
    const float* bias   = (const float*)d_in[3];
    float*       out    = (float*)d_out;

    qlin_kernel<<<dim3(OUT_F / 16), dim3(256), 0, stream>>>(x, w, scales, bias, out);
}

// Round 3
// 263.456 us; speedup vs baseline: 1.0478x; 1.0478x over previous
//
#include <hip/hip_runtime.h>
#include <hip/hip_bf16.h>

// QuantLinear: out[t,o] = scale[o] * sum_k x[t,k]*q[o,k] + bias[o]
// M=32, N=11008, K=4096. Dtypes (verified round 2): x/scales/bias/out fp32,
// qweight int32 (int8 values). Memory-bound: 180.4 MB weight stream ->
// ~29 us floor @6.3 TB/s.
// Round-3 changes: K-split 8 (512-thr blocks, 21.5 waves/CU grid -> 16/CU
// resident under VGPR<=128), x pre-converted to bf16 in d_ws (1 A-load/frag),
// unroll 4 (deep MLP on the weight stream).

constexpr int IN_F   = 4096;
constexpr int OUT_F  = 11008;
constexpr int KSLICE = IN_F / 8;   // 512 per wave

typedef short bf16x8 __attribute__((ext_vector_type(8)));  // 8 bf16 (4 VGPRs)
typedef float f32x4  __attribute__((ext_vector_type(4)));

union B8 { bf16x8 v; unsigned u[4]; };

// [hi16(lo), hi16(hi)] -> bf16 pair (truncate). Exact for int8 values.
__device__ __forceinline__ unsigned pack2f(float lo, float hi) {
    return __builtin_amdgcn_perm(__float_as_uint(hi),
                                 __float_as_uint(lo),
                                 0x07060302u);
}

// Pre-convert x fp32 -> bf16 (truncate) into workspace. 131072 elems.
__global__ __launch_bounds__(256)
void xconv_kernel(const float* __restrict__ x, unsigned* __restrict__ xb) {
    const int i = (blockIdx.x * 256 + threadIdx.x) * 4;   // float index
    float4 v = *reinterpret_cast<const float4*>(x + i);
    xb[i / 2]     = pack2f(v.x, v.y);
    xb[i / 2 + 1] = pack2f(v.z, v.w);
}

__global__ __launch_bounds__(512, 4)   // VGPR cap 128 -> 16 waves/CU
void qlin_kernel(const unsigned short* __restrict__ xb,  // bf16 bits [32][4096]
                 const int* __restrict__ w,              // int32 [11008][4096]
                 const float* __restrict__ scales,       // [11008]
                 const float* __restrict__ bias,         // [11008]
                 float* __restrict__ out)                // [32][11008]
{
    const int lane = threadIdx.x & 63;
    const int wv   = threadIdx.x >> 6;   // 0..7: K-split across 8 waves
    const int r    = lane & 15;
    const int q    = lane >> 4;

    const int n0 = blockIdx.x << 4;      // 688 blocks x 16 output rows
    const int kb = wv * KSLICE;          // 512-wide K slice per wave

    f32x4 acc0 = {0.f, 0.f, 0.f, 0.f};   // tokens 0..15
    f32x4 acc1 = {0.f, 0.f, 0.f, 0.f};   // tokens 16..31

    // A-frag: xb[m = r][k = kb + q*8 + j], one 16B load (L2-resident, 256 KB)
    const unsigned short* xp0 = xb + r * IN_F + kb + q * 8;
    const unsigned short* xp1 = xp0 + 16 * IN_F;
    // B-frag: w[n = n0+r][k = kb + q*8 + j], 8 int32 = 2x dwordx4 per lane
    const int* wp = w + (size_t)(n0 + r) * IN_F + kb + q * 8;

    #pragma unroll 4
    for (int kk = 0; kk < KSLICE; kk += 32) {
        bf16x8 a0 = *reinterpret_cast<const bf16x8*>(xp0 + kk);
        bf16x8 a1 = *reinterpret_cast<const bf16x8*>(xp1 + kk);
        int4   qa = *reinterpret_cast<const int4*>(wp + kk);
        int4   qb = *reinterpret_cast<const int4*>(wp + kk + 4);
        B8 bb;
        bb.u[0] = pack2f((float)qa.x, (float)qa.y);
        bb.u[1] = pack2f((float)qa.z, (float)qa.w);
        bb.u[2] = pack2f((float)qb.x, (float)qb.y);
        bb.u[3] = pack2f((float)qb.z, (float)qb.w);
        acc0 = __builtin_amdgcn_mfma_f32_16x16x32_bf16(a0, bb.v, acc0, 0, 0, 0);
        acc1 = __builtin_amdgcn_mfma_f32_16x16x32_bf16(a1, bb.v, acc1, 0, 0, 0);
    }

    // Cross-wave K reduction through LDS (conflict-free: lane-contiguous).
    __shared__ float red[7][2][4][64];
    if (wv > 0) {
        #pragma unroll
        for (int i = 0; i < 4; ++i) {
            red[wv - 1][0][i][lane] = acc0[i];
            red[wv - 1][1][i][lane] = acc1[i];
        }
    }
    __syncthreads();
    if (wv == 0) {
        #pragma unroll
        for (int j = 0; j < 7; ++j) {
            #pragma unroll
            for (int i = 0; i < 4; ++i) {
                acc0[i] += red[j][0][i][lane];
                acc1[i] += red[j][1][i][lane];
            }
        }
        // C/D layout (m89/m91): col n = lane&15, row m = (lane>>4)*4 + reg
        const int n = n0 + r;
        const float s = scales[n];
        const float b = bias[n];
        #pragma unroll
        for (int i = 0; i < 4; ++i) {
            out[(q * 4 + i) * OUT_F + n]      = acc0[i] * s + b;
            out[(16 + q * 4 + i) * OUT_F + n] = acc1[i] * s + b;
        }
    }
}

extern "C" void kernel_launch(void* const* d_in, const int* in_sizes, int n_in,
                              void* d_out, int out_size, void* d_ws, size_t ws_size,
                              hipStream_t stream) {
    const float* x      = (const float*)d_in[0];
    const int*   w      = (const int*)d_in[1];
    const float* scales = (const float*)d_in[2];
    const float* bias   = (const float*)d_in[3];
    float*       out    = (float*)d_out;
    unsigned*    xb     = (unsigned*)d_ws;   // bf16 x, 256 KB

    xconv_kernel<<<dim3(32 * IN_F / (256 * 4)), dim3(256), 0, stream>>>(x, xb);
    qlin_kernel<<<dim3(OUT_F / 16), dim3(512), 0, stream>>>(
        (const unsigned short*)xb, w, scales, bias, out);
}

// Round 4
// 253.093 us; speedup vs baseline: 1.0907x; 1.0409x over previous
//
#include <hip/hip_runtime.h>
#include <hip/hip_bf16.h>

// QuantLinear: out[t,o] = scale[o] * sum_k x[t,k]*q[o,k] + bias[o]
// M=32, N=11008, K=4096. x/scales/bias/out fp32, qweight int32 (int8 vals).
// 180.4 MB weight stream -> 29 us floor @6.3 TB/s.
// Round-4: weights staged via global_load_lds (outstanding bytes cost no
// VGPRs -> ~85 KB/CU in flight vs 9.2 KB Little's-law need). Per-wave
// private 8 KB chunks, XOR bank swizzle (2-way conflicts, free), barrier
// per chunk phase (compiler-guaranteed vmcnt drain, m97 pattern).

constexpr int IN_F   = 4096;
constexpr int OUT_F  = 11008;
constexpr int KSLICE = 512;            // per-wave K range (8-way K-split)
constexpr int CK     = 128;            // K ints per chunk (512 B per row)

typedef short bf16x8 __attribute__((ext_vector_type(8)));  // 8 bf16
typedef float f32x4  __attribute__((ext_vector_type(4)));

union B8 { bf16x8 v; unsigned u[4]; };

// [hi16(lo), hi16(hi)] -> bf16 pair (truncate). Exact for int8 values.
__device__ __forceinline__ unsigned pack2f(float lo, float hi) {
    return __builtin_amdgcn_perm(__float_as_uint(hi),
                                 __float_as_uint(lo),
                                 0x07060302u);
}

// x fp32 -> bf16 (truncate) into workspace. 131072 elems.
__global__ __launch_bounds__(256)
void xconv_kernel(const float* __restrict__ x, unsigned* __restrict__ xb) {
    const int i = (blockIdx.x * 256 + threadIdx.x) * 4;
    float4 v = *reinterpret_cast<const float4*>(x + i);
    xb[i / 2]     = pack2f(v.x, v.y);
    xb[i / 2 + 1] = pack2f(v.z, v.w);
}

__global__ __launch_bounds__(512, 4)   // 2 blocks/CU (also LDS-capped: 78 KB)
void qlin_kernel(const unsigned short* __restrict__ xb,  // bf16 bits [32][4096]
                 const int* __restrict__ w,              // int32 [11008][4096]
                 const float* __restrict__ scales,       // [11008]
                 const float* __restrict__ bias,         // [11008]
                 float* __restrict__ out)                // [32][11008]
{
    __shared__ int   wbuf[8][CK * 16];        // 8 waves x 8 KB weight chunk
    __shared__ float red[7][2][4][64];        // cross-wave reduction

    const int lane = threadIdx.x & 63;
    const int wv   = threadIdx.x >> 6;   // 0..7: K-split across 8 waves
    const int r    = lane & 15;
    const int q    = lane >> 4;

    const int n0 = blockIdx.x << 4;      // 688 blocks x 16 output rows
    const int kb = wv * KSLICE;

    f32x4 acc0 = {0.f, 0.f, 0.f, 0.f};   // tokens 0..15
    f32x4 acc1 = {0.f, 0.f, 0.f, 0.f};   // tokens 16..31

    // A-frags from global (L2-resident bf16 x), 16B per lane
    const unsigned short* xp0 = xb + r * IN_F + kb + q * 8;
    const unsigned short* xp1 = xp0 + 16 * IN_F;

    // LDS read view: row r at byte offset r*512 within this wave's chunk;
    // group slot s holds k-group g where s = g ^ (r&7)  (bank spread).
    const int  swz = r & 7;
    const int4* lsp = reinterpret_cast<const int4*>(&wbuf[wv][0]) + r * 32;

    for (int c = 0; c < KSLICE / CK; ++c) {
        const int kc = kb + c * CK;
        // Weight DMA: 8 x 1KB dense instructions. Instr j covers rows
        // 2j,2j+1 (512B each). LDS dst = uniform base + lane*16, which
        // lands lane l's 16B at row (2j + l>>5), slot (l&31). We choose the
        // global source so slot s holds group g = s ^ (r&7).
        #pragma unroll
        for (int j = 0; j < 8; ++j) {
            const int rj = 2 * j + (lane >> 5);
            const int gj = (lane & 31) ^ (rj & 7);
            const int* src = w + (size_t)(n0 + rj) * IN_F + kc + 4 * gj;
            __builtin_amdgcn_global_load_lds(
                (const __attribute__((address_space(1))) void*)src,
                (__attribute__((address_space(3))) void*)&wbuf[wv][j * 256],
                16, 0, 0);
        }
        // A-frag prefetch for this chunk (completes during the DMA drain).
        bf16x8 af0[4], af1[4];
        #pragma unroll
        for (int i = 0; i < 4; ++i) {
            af0[i] = *reinterpret_cast<const bf16x8*>(xp0 + c * CK + i * 32);
            af1[i] = *reinterpret_cast<const bf16x8*>(xp1 + c * CK + i * 32);
        }
        __syncthreads();   // compiler emits vmcnt(0) drain: DMA complete

        #pragma unroll
        for (int i = 0; i < 4; ++i) {
            const int G0 = i * 8 + q * 2;          // 16B k-group index
            int4 qa = lsp[G0 ^ swz];
            int4 qb = lsp[(G0 + 1) ^ swz];
            B8 bb;
            bb.u[0] = pack2f((float)qa.x, (float)qa.y);
            bb.u[1] = pack2f((float)qa.z, (float)qa.w);
            bb.u[2] = pack2f((float)qb.x, (float)qb.y);
            bb.u[3] = pack2f((float)qb.z, (float)qb.w);
            acc0 = __builtin_amdgcn_mfma_f32_16x16x32_bf16(af0[i], bb.v, acc0, 0, 0, 0);
            acc1 = __builtin_amdgcn_mfma_f32_16x16x32_bf16(af1[i], bb.v, acc1, 0, 0, 0);
        }
        __syncthreads();   // all reads done before next chunk overwrites
    }

    // Cross-wave K reduction through LDS.
    if (wv > 0) {
        #pragma unroll
        for (int i = 0; i < 4; ++i) {
            red[wv - 1][0][i][lane] = acc0[i];
            red[wv - 1][1][i][lane] = acc1[i];
        }
    }
    __syncthreads();
    if (wv == 0) {
        #pragma unroll
        for (int j = 0; j < 7; ++j) {
            #pragma unroll
            for (int i = 0; i < 4; ++i) {
                acc0[i] += red[j][0][i][lane];
                acc1[i] += red[j][1][i][lane];
            }
        }
        // C/D layout (m89/m91): col n = lane&15, row m = (lane>>4)*4 + reg
        const int n = n0 + r;
        const float s = scales[n];
        const float b = bias[n];
        #pragma unroll
        for (int i = 0; i < 4; ++i) {
            out[(q * 4 + i) * OUT_F + n]      = acc0[i] * s + b;
            out[(16 + q * 4 + i) * OUT_F + n] = acc1[i] * s + b;
        }
    }
}

extern "C" void kernel_launch(void* const* d_in, const int* in_sizes, int n_in,
                              void* d_out, int out_size, void* d_ws, size_t ws_size,
                              hipStream_t stream) {
    const float* x      = (const float*)d_in[0];
    const int*   w      = (const int*)d_in[1];
    const float* scales = (const float*)d_in[2];
    const float* bias   = (const float*)d_in[3];
    float*       out    = (float*)d_out;
    unsigned*    xb     = (unsigned*)d_ws;   // bf16 x, 256 KB

    xconv_kernel<<<dim3(32 * IN_F / (256 * 4)), dim3(256), 0, stream>>>(x, xb);
    qlin_kernel<<<dim3(OUT_F / 16), dim3(512), 0, stream>>>(
        (const unsigned short*)xb, w, scales, bias, out);
}